// Round 1
// baseline (2580.492 us; speedup 1.0000x reference)
//
#include <hip/hip_runtime.h>
#include <stdint.h>

// ---------- types / helpers ----------
typedef short s16x8 __attribute__((ext_vector_type(8)));
typedef short s16x4 __attribute__((ext_vector_type(4)));
typedef float f32x4 __attribute__((ext_vector_type(4)));
typedef unsigned short u16;

#define DEV __device__ __forceinline__

DEV float bf2f(u16 v){ union{float f; unsigned u;} x; x.u = ((unsigned)v)<<16; return x.f; }
DEV u16 f2bf(float f){ union{float f; unsigned u;} x; x.f = f; unsigned r = x.u + 0x7fffu + ((x.u>>16)&1u); return (u16)(r>>16); }
DEV float sigm(float x){ return 1.f/(1.f + __expf(-x)); }

// Problem constants
// B=64, P=196, D=2048, E=512, H=512, A=512, V=32000, S=22, T=20

enum { EPI_F32=0, EPI_BF16=1, EPI_H0C0=2, EPI_PREDS=3, EPI_LSTM=4 };

struct EpiParams {
  float* out0; long ldo;
  u16* outb;
  const float* bias0;
  const int* declen;
  float* c; u16* xh; u16* hall;
  const float* gst; int t;
};

// ---------- generic MFMA GEMM: C[M][N] = A[M][K](bf16) * B[N][K](bf16)^T ----------
// B is stored N-major ("BT layout"). BK=64 fixed. 256 threads (4 waves).
template<int BM, int BN, int EPI>
__global__ __launch_bounds__(256) void gemm_bt(
    const u16* __restrict__ A, long lda,
    const u16* __restrict__ B, long ldb,
    int K, EpiParams ep)
{
  static_assert(BM==64 || BM==128, "");
  constexpr int MF = BM/64;          // m-fragments per wave
  constexpr int NF = BN/16;          // n-fragments per wave
  constexpr int CHA = BM*8, CH = CHA + BN*8;   // 16B chunks per K-tile
  __shared__ char smem[(BM+BN)*128];
  char* Al = smem;
  char* Bl = smem + BM*128;
  const int tid = threadIdx.x;
  const int w = tid>>6, lane = tid&63;
  const long arow0 = (long)blockIdx.y * BM;
  const long brow0 = (long)blockIdx.x * BN;

  f32x4 acc[MF][NF];
  #pragma unroll
  for (int i=0;i<MF;++i)
    #pragma unroll
    for (int j=0;j<NF;++j) acc[i][j] = (f32x4){0.f,0.f,0.f,0.f};

  const int KT = K >> 6;
  for (int kt = 0; kt < KT; ++kt) {
    const long kb = (long)kt*64;
    #pragma unroll
    for (int c0 = 0; c0 < CH; c0 += 256) {
      int c = c0 + tid;
      if (c < CHA) {
        int row = c>>3, k16 = c&7;
        s16x8 v = *(const s16x8*)(A + (arow0+row)*lda + kb + k16*8);
        *(s16x8*)(Al + row*128 + ((k16*16) ^ ((row&7)<<4))) = v;
      } else {
        int cb = c - CHA;
        int row = cb>>3, k16 = cb&7;
        s16x8 v = *(const s16x8*)(B + (brow0+row)*ldb + kb + k16*8);
        *(s16x8*)(Bl + row*128 + ((k16*16) ^ ((row&7)<<4))) = v;
      }
    }
    __syncthreads();
    #pragma unroll
    for (int ks = 0; ks < 2; ++ks) {
      s16x8 af[MF], bfr[NF];
      const int kboff = ks*64 + ((lane>>4)<<4);
      #pragma unroll
      for (int mf=0; mf<MF; ++mf) {
        int r = w*(16*MF) + mf*16 + (lane&15);
        af[mf] = *(const s16x8*)(Al + r*128 + (kboff ^ ((r&7)<<4)));
      }
      #pragma unroll
      for (int nf=0; nf<NF; ++nf) {
        int r = nf*16 + (lane&15);
        bfr[nf] = *(const s16x8*)(Bl + r*128 + (kboff ^ ((r&7)<<4)));
      }
      #pragma unroll
      for (int mf=0; mf<MF; ++mf)
        #pragma unroll
        for (int nf=0; nf<NF; ++nf)
          acc[mf][nf] = __builtin_amdgcn_mfma_f32_16x16x32_bf16(af[mf], bfr[nf], acc[mf][nf], 0,0,0);
    }
    __syncthreads();
  }

  if constexpr (EPI == EPI_LSTM) {
    // BM==64 here. Gate pre-activations -> LDS, then fused LSTM pointwise.
    float* G = (float*)smem;
    #pragma unroll
    for (int nf=0; nf<NF; ++nf)
      #pragma unroll
      for (int r=0; r<4; ++r) {
        int ml = w*16 + ((lane>>4)<<2) + r;     // batch b
        int nl = nf*16 + (lane&15);             // permuted gate row (local)
        G[ml*BN + nl] = acc[0][nf][r]
            + ep.gst[((long)ep.t*64 + arow0 + ml)*2048 + brow0 + nl];
      }
    __syncthreads();
    constexpr int JB = BN/4;
    const int j0 = ((int)brow0)>>2;
    for (int it = tid; it < 64*JB; it += 256) {
      int b = it/JB, jl = it - b*JB;
      const float* gp = G + b*BN + jl*4;       // rows 4j+g : g = i,f,gg,o
      float gi = gp[0], gf = gp[1], gg = gp[2], go = gp[3];
      int j = j0 + jl;
      float cc = ep.c[b*512 + j];
      float cn = sigm(gf)*cc + sigm(gi)*tanhf(gg);
      float hn = sigm(go)*tanhf(cn);
      ep.c[b*512 + j] = cn;
      u16 hb = f2bf(hn);
      ep.xh[b*2560 + 2048 + j] = hb;                       // h slice of next GEMM A
      ep.hall[((long)ep.t*64 + b)*512 + j] = hb;           // for batched preds GEMM
    }
  } else {
    #pragma unroll
    for (int mf=0; mf<MF; ++mf)
      #pragma unroll
      for (int nf=0; nf<NF; ++nf)
        #pragma unroll
        for (int r=0; r<4; ++r) {
          long m = arow0 + w*(16*MF) + mf*16 + ((lane>>4)<<2) + r;
          long n = brow0 + nf*16 + (lane&15);
          float v = acc[mf][nf][r] + ep.bias0[n];
          if constexpr (EPI == EPI_F32) {
            ep.out0[m*ep.ldo + n] = v;
          } else if constexpr (EPI == EPI_BF16) {
            ep.outb[m*ep.ldo + n] = f2bf(v);
          } else if constexpr (EPI == EPI_H0C0) {
            if (n < 512) ep.xh[m*2560 + 2048 + n] = f2bf(v);   // h0
            else         ep.c[m*512 + (n-512)] = v;            // c0
          } else { // EPI_PREDS : m = t*64+b -> out[b][t][n], masked
            int t = (int)(m>>6), b = (int)(m&63);
            ep.out0[(long)b*640000 + (long)t*32000 + n] = (ep.declen[b] > t) ? v : 0.f;
          }
        }
  }
}

// ---------- transpose f32[R][C] -> bf16[C][R] ----------
__global__ __launch_bounds__(256) void transpose_bf16(
    const float* __restrict__ in, u16* __restrict__ out, int R, int C)
{
  __shared__ float t[64][65];
  const int bx = blockIdx.x*64, by = blockIdx.y*64;
  const int tx = threadIdx.x & 63, ty = threadIdx.x >> 6;
  #pragma unroll
  for (int i=0;i<16;++i){ int r = i*4+ty; t[r][tx] = in[(long)(by+r)*C + bx+tx]; }
  __syncthreads();
  #pragma unroll
  for (int i=0;i<16;++i){ int cc = i*4+ty; out[(long)(bx+cc)*R + by+tx] = f2bf(t[tx][cc]); }
}

// ---------- stable descending argsort of 64 lengths + small outputs ----------
__global__ void sort_k(const int* __restrict__ cl, const int* __restrict__ captions,
                       int* __restrict__ sidx, int* __restrict__ declen,
                       float* __restrict__ outCaps, float* __restrict__ outLens,
                       float* __restrict__ outSidx)
{
  __shared__ int s_idx[64];
  int i = threadIdx.x;
  int li = cl[i];
  int rank = 0;
  for (int j=0;j<64;++j){ int lj = cl[j]; rank += (lj>li) || (lj==li && j<i); }
  s_idx[rank] = i;
  __syncthreads();
  int src = s_idx[i];
  sidx[i] = src;
  int L = cl[src];
  declen[i] = L - 1;
  outLens[i] = (float)L;
  outSidx[i] = (float)src;
  for (int s=0;s<22;++s) outCaps[i*22+s] = (float)captions[s*64 + src];
}

// ---------- gather sorted enc -> bf16 + per-(b,d) mean ----------
__global__ __launch_bounds__(256) void prep_enc(
    const float* __restrict__ features, const int* __restrict__ sidx,
    u16* __restrict__ enc, u16* __restrict__ meanb)
{
  int b = blockIdx.x >> 1, dh = blockIdx.x & 1;
  int d0 = dh*1024 + threadIdx.x*4;
  const float* src = features + (long)sidx[b]*(196*2048) + d0;
  float acc[4] = {0.f,0.f,0.f,0.f};
  for (int p=0;p<196;++p){
    f32x4 v = *(const f32x4*)(src + (long)p*2048);
    u16 o[4];
    #pragma unroll
    for (int q=0;q<4;++q){ acc[q] += v[q]; o[q] = f2bf(v[q]); }
    *(s16x4*)(enc + ((long)b*196 + p)*2048 + d0) = *(s16x4*)o;
  }
  u16 mo[4];
  #pragma unroll
  for (int q=0;q<4;++q) mo[q] = f2bf(acc[q]*(1.f/196.f));
  *(s16x4*)(meanb + b*2048 + d0) = *(s16x4*)mo;
}

// ---------- gather embeddings for t<20 -> bf16 [t*64+b][512] ----------
__global__ void emb_gather(const int* __restrict__ captions, const int* __restrict__ sidx,
                           const float* __restrict__ embW, u16* __restrict__ out)
{
  int idx = blockIdx.x*256 + threadIdx.x;      // 1280*64
  int row = idx >> 6; int e0 = (idx & 63)*8;
  int t = row >> 6, b = row & 63;
  int tok = captions[t*64 + sidx[b]];
  const float* s = embW + (long)tok*512 + e0;
  f32x4 v0 = *(const f32x4*)s, v1 = *(const f32x4*)(s+4);
  u16 o[8];
  #pragma unroll
  for (int q=0;q<4;++q){ o[q] = f2bf(v0[q]); o[4+q] = f2bf(v1[q]); }
  *(s16x8*)(out + (long)row*512 + e0) = *(s16x8*)o;
}

// ---------- weight packers ----------
// Wcat2[(4j+g)][k] : k<2048 -> Wih[g*512+j][512+k] ; else Whh[g*512+j][k-2048]
__global__ void build_wcat2(const float* __restrict__ Wih, const float* __restrict__ Whh,
                            u16* __restrict__ out)
{
  long idx = (long)blockIdx.x*256 + threadIdx.x;   // 2048*320
  int r = (int)(idx / 320);
  int kc = (int)(idx % 320) * 8;
  int j = r>>2, g = r&3;
  int orow = g*512 + j;
  const float* s = (kc < 2048) ? (Wih + (long)orow*2560 + 512 + kc)
                               : (Whh + (long)orow*512 + (kc - 2048));
  f32x4 v0 = *(const f32x4*)s, v1 = *(const f32x4*)(s+4);
  u16 o[8];
  #pragma unroll
  for (int q=0;q<4;++q){ o[q] = f2bf(v0[q]); o[4+q] = f2bf(v1[q]); }
  *(s16x8*)(out + (long)r*2560 + kc) = *(s16x8*)o;
}

// Wihe[(4j+g)][k] = Wih[g*512+j][k], k<512
__global__ void build_wihe(const float* __restrict__ Wih, u16* __restrict__ out)
{
  int idx = blockIdx.x*256 + threadIdx.x;          // 2048*64
  int r = idx >> 6; int kc = (idx & 63)*8;
  int j = r>>2, g = r&3;
  const float* s = Wih + (long)(g*512+j)*2560 + kc;
  f32x4 v0 = *(const f32x4*)s, v1 = *(const f32x4*)(s+4);
  u16 o[8];
  #pragma unroll
  for (int q=0;q<4;++q){ o[q] = f2bf(v0[q]); o[4+q] = f2bf(v1[q]); }
  *(s16x8*)(out + (long)r*512 + kc) = *(s16x8*)o;
}

__global__ void build_bias(const float* bih, const float* bhh, const float* bbeta,
                           const float* bd, const float* bh0, const float* bc0,
                           float* bstat, float* bmisc, float* bhc)
{
  int idx = blockIdx.x*256 + threadIdx.x;
  if (idx < 2048){ int j = idx>>2, g = idx&3; bstat[idx] = bih[g*512+j] + bhh[g*512+j]; }
  else if (idx < 4608){ int k = idx-2048; bmisc[k] = (k<2048) ? bbeta[k] : bd[k-2048]; }
  else if (idx < 5632){ int k = idx-4608; bhc[k] = (k<512) ? bh0[k] : bc0[k-512]; }
}

// ---------- per-step fused attention: scores -> softmax -> awe -> gate*awe ----------
__global__ __launch_bounds__(256) void attn_k(
    const u16* __restrict__ att1, const float* __restrict__ Y0,
    const float* __restrict__ wf, const float* __restrict__ bfp,
    const u16* __restrict__ enc, const int* __restrict__ declen, int t,
    u16* __restrict__ xh, float* __restrict__ alph_out)
{
  __shared__ float att2s[512], wfs[512], red[256], sc[196], alps[196];
  const int b = blockIdx.x, tid = threadIdx.x;
  att2s[tid]     = Y0[b*2560 + 2048 + tid];
  att2s[tid+256] = Y0[b*2560 + 2048 + 256 + tid];
  wfs[tid] = wf[tid]; wfs[tid+256] = wf[tid+256];
  __syncthreads();
  const int w = tid>>6, lane = tid&63;
  const float bfv = bfp[0];
  for (int p = w; p < 196; p += 4) {
    s16x8 v = *(const s16x8*)(att1 + (((long)(b*196 + p))<<9) + lane*8);
    float s = 0.f;
    #pragma unroll
    for (int q=0;q<8;++q){
      float x = bf2f((u16)v[q]) + att2s[lane*8+q];
      x = fmaxf(x, 0.f);
      s += x * wfs[lane*8+q];
    }
    #pragma unroll
    for (int off=32; off; off>>=1) s += __shfl_xor(s, off);
    if (lane==0) sc[p] = s + bfv;
  }
  __syncthreads();
  float v = (tid<196) ? sc[tid] : -3.4e38f;
  red[tid] = v; __syncthreads();
  #pragma unroll
  for (int s2=128; s2>0; s2>>=1){ if (tid<s2) red[tid] = fmaxf(red[tid], red[tid+s2]); __syncthreads(); }
  float mx = red[0];
  __syncthreads();
  float e = (tid<196) ? __expf(v - mx) : 0.f;
  red[tid] = e; __syncthreads();
  #pragma unroll
  for (int s2=128; s2>0; s2>>=1){ if (tid<s2) red[tid] += red[tid+s2]; __syncthreads(); }
  float inv = 1.f / red[0];
  if (tid < 196){
    float a = e * inv;
    alps[tid] = a;
    alph_out[((long)b*20 + t)*196 + tid] = (declen[b] > t) ? a : 0.f;
  }
  __syncthreads();
  const int d0 = tid*8;
  float acc[8] = {0.f,0.f,0.f,0.f,0.f,0.f,0.f,0.f};
  for (int p=0;p<196;++p){
    s16x8 ev = *(const s16x8*)(enc + ((((long)b*196) + p)<<11) + d0);
    float a = alps[p];
    #pragma unroll
    for (int q=0;q<8;++q) acc[q] += a * bf2f((u16)ev[q]);
  }
  u16 o[8];
  #pragma unroll
  for (int q=0;q<8;++q){
    float gate = sigm(Y0[b*2560 + d0 + q]);
    o[q] = f2bf(gate * acc[q]);
  }
  *(s16x8*)(xh + (long)b*2560 + d0) = *(s16x8*)o;
}

// ---------- workspace layout (bytes) ----------
static constexpr long OFF_ENC   = 0;                 // 64*196*2048 bf16
static constexpr long OFF_ATT1  = 51380224;          // 12544*512 bf16
static constexpr long OFF_WOUTT = 64225280;          // 32000*512 bf16
static constexpr long OFF_WET   = 96993280;          // 512*2048 bf16
static constexpr long OFF_WMISC = 99090432;          // 2560*512 bf16 (Wbeta^T ; Wd^T)
static constexpr long OFF_WHC   = 101711872;         // 1024*2048 bf16 (Wh0^T ; Wc0^T)
static constexpr long OFF_WCAT2 = 105906176;         // 2048*2560 bf16 (perm [Wih_a|Whh])
static constexpr long OFF_WIHE  = 116391936;         // 2048*512 bf16 (perm Wih_e)
static constexpr long OFF_EMBB  = 118489088;         // 1280*512 bf16
static constexpr long OFF_GST   = 119799808;         // 1280*2048 f32
static constexpr long OFF_HALL  = 130285568;         // 1280*512 bf16
static constexpr long OFF_MEANB = 131596288;         // 64*2048 bf16
static constexpr long OFF_XH    = 131858432;         // 64*2560 bf16
static constexpr long OFF_C     = 132186112;         // 64*512 f32
static constexpr long OFF_Y0    = 132317184;         // 64*2560 f32
static constexpr long OFF_BSTAT = 132972544;         // 2048 f32
static constexpr long OFF_BMISC = 132980736;         // 2560 f32
static constexpr long OFF_BHC   = 132990976;         // 1024 f32
static constexpr long OFF_SIDX  = 132995072;         // 64 int
static constexpr long OFF_DECL  = 132995328;         // 64 int

extern "C" void kernel_launch(void* const* d_in, const int* in_sizes, int n_in,
                              void* d_out, int out_size, void* d_ws, size_t ws_size,
                              hipStream_t stream)
{
  (void)in_sizes; (void)n_in; (void)out_size; (void)ws_size;
  const float* features = (const float*)d_in[0];
  const int*   captions = (const int*)d_in[1];
  const int*   caplen   = (const int*)d_in[2];
  const float* embW     = (const float*)d_in[3];
  const float* We       = (const float*)d_in[4];
  const float* be       = (const float*)d_in[5];
  const float* Wd       = (const float*)d_in[6];
  const float* bd       = (const float*)d_in[7];
  const float* wf       = (const float*)d_in[8];
  const float* bfp      = (const float*)d_in[9];
  const float* Wih      = (const float*)d_in[10];
  const float* Whh      = (const float*)d_in[11];
  const float* bih      = (const float*)d_in[12];
  const float* bhh      = (const float*)d_in[13];
  const float* Wh0      = (const float*)d_in[14];
  const float* bh0      = (const float*)d_in[15];
  const float* Wc0      = (const float*)d_in[16];
  const float* bc0      = (const float*)d_in[17];
  const float* Wbeta    = (const float*)d_in[18];
  const float* bbeta    = (const float*)d_in[19];
  const float* Wout     = (const float*)d_in[20];
  const float* bout     = (const float*)d_in[21];

  char* ws = (char*)d_ws;
  u16*   enc   = (u16*)(ws + OFF_ENC);
  u16*   att1  = (u16*)(ws + OFF_ATT1);
  u16*   woutt = (u16*)(ws + OFF_WOUTT);
  u16*   wet   = (u16*)(ws + OFF_WET);
  u16*   wmisc = (u16*)(ws + OFF_WMISC);
  u16*   whc   = (u16*)(ws + OFF_WHC);
  u16*   wcat2 = (u16*)(ws + OFF_WCAT2);
  u16*   wihe  = (u16*)(ws + OFF_WIHE);
  u16*   embb  = (u16*)(ws + OFF_EMBB);
  float* gst   = (float*)(ws + OFF_GST);
  u16*   hall  = (u16*)(ws + OFF_HALL);
  u16*   meanb = (u16*)(ws + OFF_MEANB);
  u16*   xh    = (u16*)(ws + OFF_XH);
  float* cbuf  = (float*)(ws + OFF_C);
  float* y0    = (float*)(ws + OFF_Y0);
  float* bstat = (float*)(ws + OFF_BSTAT);
  float* bmisc = (float*)(ws + OFF_BMISC);
  float* bhc   = (float*)(ws + OFF_BHC);
  int*   sidx  = (int*)(ws + OFF_SIDX);
  int*   declen= (int*)(ws + OFF_DECL);

  float* outP    = (float*)d_out;            // [64][20][32000]
  float* outCaps = outP + 40960000;          // [64][22]
  float* outLens = outCaps + 1408;           // [64]
  float* outAlph = outLens + 64;             // [64][20][196]
  float* outSidx = outAlph + 250880;         // [64]

  // ---- setup ----
  sort_k<<<1,64,0,stream>>>(caplen, captions, sidx, declen, outCaps, outLens, outSidx);
  prep_enc<<<128,256,0,stream>>>(features, sidx, enc, meanb);
  emb_gather<<<320,256,0,stream>>>(captions, sidx, embW, embb);
  transpose_bf16<<<dim3(8,32),256,0,stream>>>(We,    wet,              2048, 512);
  transpose_bf16<<<dim3(32,8),256,0,stream>>>(Wbeta, wmisc,            512, 2048);
  transpose_bf16<<<dim3(8,8), 256,0,stream>>>(Wd,    wmisc + 2048*512, 512, 512);
  transpose_bf16<<<dim3(8,32),256,0,stream>>>(Wh0,   whc,              2048, 512);
  transpose_bf16<<<dim3(8,32),256,0,stream>>>(Wc0,   whc + 512*2048,   2048, 512);
  transpose_bf16<<<dim3(500,8),256,0,stream>>>(Wout, woutt,            512, 32000);
  build_wcat2<<<2560,256,0,stream>>>(Wih, Whh, wcat2);
  build_wihe<<<512,256,0,stream>>>(Wih, wihe);
  build_bias<<<22,256,0,stream>>>(bih,bhh,bbeta,bd,bh0,bc0,bstat,bmisc,bhc);

  // h0/c0 : mean @ [Wh0|Wc0]
  { EpiParams ep{}; ep.bias0 = bhc; ep.xh = xh; ep.c = cbuf;
    gemm_bt<64,64,EPI_H0C0><<<dim3(16,1),256,0,stream>>>(meanb, 2048, whc, 2048, 2048, ep); }
  // att1 = enc @ We + be  (bf16 out)
  { EpiParams ep{}; ep.outb = att1; ep.ldo = 512; ep.bias0 = be;
    gemm_bt<128,128,EPI_BF16><<<dim3(4,98),256,0,stream>>>(enc, 2048, wet, 2048, 2048, ep); }
  // g_static[t,b,:] = e_t @ Wih_e^T + bih + bhh (permuted cols)
  { EpiParams ep{}; ep.out0 = gst; ep.ldo = 2048; ep.bias0 = bstat;
    gemm_bt<128,64,EPI_F32><<<dim3(32,10),256,0,stream>>>(embb, 512, wihe, 512, 512, ep); }

  // ---- 20 sequential steps ----
  for (int t=0; t<20; ++t){
    { EpiParams ep{}; ep.out0 = y0; ep.ldo = 2560; ep.bias0 = bmisc;   // gatez | att2
      gemm_bt<64,64,EPI_F32><<<dim3(40,1),256,0,stream>>>(xh + 2048, 2560, wmisc, 512, 512, ep); }
    attn_k<<<64,256,0,stream>>>(att1, y0, wf, bfp, enc, declen, t, xh, outAlph);
    { EpiParams ep{}; ep.gst = gst; ep.t = t; ep.c = cbuf; ep.xh = xh; ep.hall = hall;
      gemm_bt<64,32,EPI_LSTM><<<dim3(64,1),256,0,stream>>>(xh, 2560, wcat2, 2560, 2560, ep); }
  }

  // ---- batched predictions: h_all @ Wout + bout, masked ----
  { EpiParams ep{}; ep.out0 = outP; ep.bias0 = bout; ep.declen = declen;
    gemm_bt<128,64,EPI_PREDS><<<dim3(500,10),256,0,stream>>>(hall, 512, woutt, 512, 512, ep); }
}

// Round 2
// 2140.330 us; speedup vs baseline: 1.2057x; 1.2057x over previous
//
#include <hip/hip_runtime.h>
#include <stdint.h>

// ---------- types / helpers ----------
typedef short s16x8 __attribute__((ext_vector_type(8)));
typedef short s16x4 __attribute__((ext_vector_type(4)));
typedef float f32x4 __attribute__((ext_vector_type(4)));
typedef unsigned short u16;

#define DEV __device__ __forceinline__

DEV float bf2f(u16 v){ union{float f; unsigned u;} x; x.u = ((unsigned)v)<<16; return x.f; }
DEV u16 f2bf(float f){ union{float f; unsigned u;} x; x.f = f; unsigned r = x.u + 0x7fffu + ((x.u>>16)&1u); return (u16)(r>>16); }
DEV float sigm(float x){ return 1.f/(1.f + __expf(-x)); }

// B=64, P=196, D=2048, E=512, H=512, A=512, V=32000, S=22, T=20

enum { EPI_F32=0, EPI_BF16=1, EPI_H0C0=2, EPI_PREDS=3, EPI_LSTM=4 };

struct EpiParams {
  float* out0; long ldo; long pstride;
  u16* outb;
  const float* bias0;
  const int* declen;
  float* c; u16* xh; u16* hall;
  const float* gst; int t;
  float* part; int* cnt;
};

// ---------- generic MFMA GEMM: C[M][N] = A[M][K](bf16) * B[N][K](bf16)^T ----------
// 2-phase reg-staged prefetch; optional split-K (M must be 64, blockIdx.y = split);
// optional SWAPXY (blockIdx.x -> M tile) for L2 B-panel reuse.
template<int BM, int BN, int EPI, int KSPLIT, bool SWAPXY>
__global__ __launch_bounds__(256) void gemm_bt(
    const u16* __restrict__ A, long lda,
    const u16* __restrict__ B, long ldb,
    int K, EpiParams ep)
{
  constexpr int MF = BM/64;          // m-fragments per wave
  constexpr int NF = BN/16;          // n-fragments per wave
  constexpr int CHA = BM*8, CH = CHA + BN*8;   // 16B chunks per K-tile
  constexpr int NST = CH/256;        // staging chunks per thread
  __shared__ char smem[(BM+BN)*128];
  const int tid = threadIdx.x;
  const int w = tid>>6, lane = tid&63;

  int split = 0;
  long arow0, brow0;
  if constexpr (KSPLIT > 1) { split = blockIdx.y; arow0 = 0; brow0 = (long)blockIdx.x*BN; }
  else if constexpr (SWAPXY) { arow0 = (long)blockIdx.x*BM; brow0 = (long)blockIdx.y*BN; }
  else { arow0 = (long)blockIdx.y*BM; brow0 = (long)blockIdx.x*BN; }

  // precompute per-chunk source pointers and swizzled LDS offsets
  const u16* gsrc[NST]; int ldst[NST];
  #pragma unroll
  for (int i=0;i<NST;++i){
    int c = i*256 + tid;
    if (i*256 < CHA){
      int row = c>>3, k16 = c&7;
      gsrc[i] = A + (arow0+row)*lda + k16*8;
      ldst[i] = row*128 + ((k16*16) ^ ((row&7)<<4));
    } else {
      int cb = c - CHA; int row = cb>>3, k16 = cb&7;
      gsrc[i] = B + (brow0+row)*ldb + k16*8;
      ldst[i] = BM*128 + row*128 + ((k16*16) ^ ((row&7)<<4));
    }
  }

  f32x4 acc[MF][NF];
  #pragma unroll
  for (int i=0;i<MF;++i)
    #pragma unroll
    for (int j=0;j<NF;++j) acc[i][j] = (f32x4){0.f,0.f,0.f,0.f};

  const int KT = K >> 6;
  const int nkt = (KSPLIT>1) ? (KT/KSPLIT) : KT;
  const int kt0 = (KSPLIT>1) ? split*nkt : 0;

  s16x8 st[NST];
  #pragma unroll
  for (int i=0;i<NST;++i) st[i] = *(const s16x8*)(gsrc[i] + (long)kt0*64);

  char* Al = smem;
  for (int kk=0; kk<nkt; ++kk){
    #pragma unroll
    for (int i=0;i<NST;++i) *(s16x8*)(smem + ldst[i]) = st[i];
    __syncthreads();
    if (kk+1 < nkt){
      long kb = (long)(kt0+kk+1)*64;
      #pragma unroll
      for (int i=0;i<NST;++i) st[i] = *(const s16x8*)(gsrc[i] + kb);
    }
    #pragma unroll
    for (int ks = 0; ks < 2; ++ks) {
      s16x8 af[MF], bfr[NF];
      const int kboff = ks*64 + ((lane>>4)<<4);
      #pragma unroll
      for (int mf=0; mf<MF; ++mf) {
        int r = w*(16*MF) + mf*16 + (lane&15);
        af[mf] = *(const s16x8*)(Al + r*128 + (kboff ^ ((r&7)<<4)));
      }
      #pragma unroll
      for (int nf=0; nf<NF; ++nf) {
        int r = nf*16 + (lane&15);
        bfr[nf] = *(const s16x8*)(Al + BM*128 + r*128 + (kboff ^ ((r&7)<<4)));
      }
      #pragma unroll
      for (int mf=0; mf<MF; ++mf)
        #pragma unroll
        for (int nf=0; nf<NF; ++nf)
          acc[mf][nf] = __builtin_amdgcn_mfma_f32_16x16x32_bf16(af[mf], bfr[nf], acc[mf][nf], 0,0,0);
    }
    __syncthreads();
  }

  if constexpr (EPI == EPI_LSTM) {
    // split-K partial write (BM=64, NF=2)
    float* PS = ep.part + (long)split*(64*2048);
    #pragma unroll
    for (int nf=0; nf<NF; ++nf)
      #pragma unroll
      for (int r=0; r<4; ++r) {
        int ml = w*16 + ((lane>>4)<<2) + r;
        int nl = nf*16 + (lane&15);
        PS[ml*2048 + brow0 + nl] = acc[0][nf][r];
      }
    __threadfence();
    __shared__ int lastf;
    if (tid==0){ int v = atomicAdd(ep.cnt + ep.t*64 + blockIdx.x, 1); lastf = (v == KSPLIT-1); }
    __syncthreads();
    if (!lastf) return;
    __threadfence();
    const int j0 = (int)(brow0 >> 2);
    for (int it = tid; it < 512; it += 256){
      int b = it>>3, jl = it&7, j = j0 + jl;
      float g4[4];
      #pragma unroll
      for (int gi=0; gi<4; ++gi){
        long n = brow0 + jl*4 + gi;
        float s = ep.gst[((long)ep.t*64 + b)*2048 + n];
        #pragma unroll
        for (int sp=0; sp<KSPLIT; ++sp)
          s += __hip_atomic_load(ep.part + (long)sp*(64*2048) + (long)b*2048 + n,
                                 __ATOMIC_RELAXED, __HIP_MEMORY_SCOPE_AGENT);
        g4[gi] = s;
      }
      float cc = ep.c[b*512 + j];
      float cn = sigm(g4[1])*cc + sigm(g4[0])*tanhf(g4[2]);
      float hn = sigm(g4[3])*tanhf(cn);
      ep.c[b*512 + j] = cn;
      u16 hb = f2bf(hn);
      ep.xh[b*2560 + 2048 + j] = hb;                 // NEXT step's xh buffer
      ep.hall[((long)ep.t*64 + b)*512 + j] = hb;
    }
  } else {
    #pragma unroll
    for (int mf=0; mf<MF; ++mf)
      #pragma unroll
      for (int nf=0; nf<NF; ++nf)
        #pragma unroll
        for (int r=0; r<4; ++r) {
          long m = arow0 + w*(16*MF) + mf*16 + ((lane>>4)<<2) + r;
          long n = brow0 + nf*16 + (lane&15);
          float bv = ep.bias0[n];
          if constexpr (EPI == EPI_F32) { if (split != 0) bv = 0.f; }
          float v = acc[mf][nf][r] + bv;
          if constexpr (EPI == EPI_F32) {
            ep.out0[(long)split*ep.pstride + m*ep.ldo + n] = v;
          } else if constexpr (EPI == EPI_BF16) {
            ep.outb[m*ep.ldo + n] = f2bf(v);
          } else if constexpr (EPI == EPI_H0C0) {
            if (n < 512) ep.xh[m*2560 + 2048 + n] = f2bf(v);   // h0
            else         ep.c[m*512 + (n-512)] = v;            // c0
          } else { // EPI_PREDS : m = t*64+b -> out[b][t][n], masked
            int t = (int)(m>>6), b = (int)(m&63);
            ep.out0[(long)b*640000 + (long)t*32000 + n] = (ep.declen[b] > t) ? v : 0.f;
          }
        }
  }
}

// ---------- transpose f32[R][C] -> bf16[C][R] ----------
__global__ __launch_bounds__(256) void transpose_bf16(
    const float* __restrict__ in, u16* __restrict__ out, int R, int C)
{
  __shared__ float t[64][65];
  const int bx = blockIdx.x*64, by = blockIdx.y*64;
  const int tx = threadIdx.x & 63, ty = threadIdx.x >> 6;
  #pragma unroll
  for (int i=0;i<16;++i){ int r = i*4+ty; t[r][tx] = in[(long)(by+r)*C + bx+tx]; }
  __syncthreads();
  #pragma unroll
  for (int i=0;i<16;++i){ int cc = i*4+ty; out[(long)(bx+cc)*R + by+tx] = f2bf(t[tx][cc]); }
}

// ---------- stable descending argsort of 64 lengths + small outputs + cnt zero ----------
__global__ void sort_k(const int* __restrict__ cl, const int* __restrict__ captions,
                       int* __restrict__ sidx, int* __restrict__ declen,
                       float* __restrict__ outCaps, float* __restrict__ outLens,
                       float* __restrict__ outSidx, int* __restrict__ cnt)
{
  __shared__ int s_idx[64];
  int i = threadIdx.x;
  int li = cl[i];
  int rank = 0;
  for (int j=0;j<64;++j){ int lj = cl[j]; rank += (lj>li) || (lj==li && j<i); }
  s_idx[rank] = i;
  __syncthreads();
  int src = s_idx[i];
  sidx[i] = src;
  int L = cl[src];
  declen[i] = L - 1;
  outLens[i] = (float)L;
  outSidx[i] = (float)src;
  for (int s=0;s<22;++s) outCaps[i*22+s] = (float)captions[s*64 + src];
  for (int s=0;s<20;++s) cnt[s*64 + i] = 0;
}

// ---------- gather sorted enc -> bf16 + per-(b,d) mean ----------
__global__ __launch_bounds__(256) void prep_enc(
    const float* __restrict__ features, const int* __restrict__ sidx,
    u16* __restrict__ enc, u16* __restrict__ meanb)
{
  int b = blockIdx.x >> 1, dh = blockIdx.x & 1;
  int d0 = dh*1024 + threadIdx.x*4;
  const float* src = features + (long)sidx[b]*(196*2048) + d0;
  float acc[4] = {0.f,0.f,0.f,0.f};
  for (int p=0;p<196;++p){
    f32x4 v = *(const f32x4*)(src + (long)p*2048);
    u16 o[4];
    #pragma unroll
    for (int q=0;q<4;++q){ acc[q] += v[q]; o[q] = f2bf(v[q]); }
    *(s16x4*)(enc + ((long)b*196 + p)*2048 + d0) = *(s16x4*)o;
  }
  u16 mo[4];
  #pragma unroll
  for (int q=0;q<4;++q) mo[q] = f2bf(acc[q]*(1.f/196.f));
  *(s16x4*)(meanb + b*2048 + d0) = *(s16x4*)mo;
}

// ---------- gather embeddings for t<20 -> bf16 [t*64+b][512] ----------
__global__ void emb_gather(const int* __restrict__ captions, const int* __restrict__ sidx,
                           const float* __restrict__ embW, u16* __restrict__ out)
{
  int idx = blockIdx.x*256 + threadIdx.x;      // 1280*64
  int row = idx >> 6; int e0 = (idx & 63)*8;
  int t = row >> 6, b = row & 63;
  int tok = captions[t*64 + sidx[b]];
  const float* s = embW + (long)tok*512 + e0;
  f32x4 v0 = *(const f32x4*)s, v1 = *(const f32x4*)(s+4);
  u16 o[8];
  #pragma unroll
  for (int q=0;q<4;++q){ o[q] = f2bf(v0[q]); o[4+q] = f2bf(v1[q]); }
  *(s16x8*)(out + (long)row*512 + e0) = *(s16x8*)o;
}

// ---------- weight packers ----------
__global__ void build_wcat2(const float* __restrict__ Wih, const float* __restrict__ Whh,
                            u16* __restrict__ out)
{
  long idx = (long)blockIdx.x*256 + threadIdx.x;   // 2048*320
  int r = (int)(idx / 320);
  int kc = (int)(idx % 320) * 8;
  int j = r>>2, g = r&3;
  int orow = g*512 + j;
  const float* s = (kc < 2048) ? (Wih + (long)orow*2560 + 512 + kc)
                               : (Whh + (long)orow*512 + (kc - 2048));
  f32x4 v0 = *(const f32x4*)s, v1 = *(const f32x4*)(s+4);
  u16 o[8];
  #pragma unroll
  for (int q=0;q<4;++q){ o[q] = f2bf(v0[q]); o[4+q] = f2bf(v1[q]); }
  *(s16x8*)(out + (long)r*2560 + kc) = *(s16x8*)o;
}

__global__ void build_wihe(const float* __restrict__ Wih, u16* __restrict__ out)
{
  int idx = blockIdx.x*256 + threadIdx.x;          // 2048*64
  int r = idx >> 6; int kc = (idx & 63)*8;
  int j = r>>2, g = r&3;
  const float* s = Wih + (long)(g*512+j)*2560 + kc;
  f32x4 v0 = *(const f32x4*)s, v1 = *(const f32x4*)(s+4);
  u16 o[8];
  #pragma unroll
  for (int q=0;q<4;++q){ o[q] = f2bf(v0[q]); o[4+q] = f2bf(v1[q]); }
  *(s16x8*)(out + (long)r*512 + kc) = *(s16x8*)o;
}

__global__ void build_bias(const float* bih, const float* bhh, const float* bbeta,
                           const float* bd, const float* bh0, const float* bc0,
                           float* bstat, float* bmisc, float* bhc)
{
  int idx = blockIdx.x*256 + threadIdx.x;
  if (idx < 2048){ int j = idx>>2, g = idx&3; bstat[idx] = bih[g*512+j] + bhh[g*512+j]; }
  else if (idx < 4608){ int k = idx-2048; bmisc[k] = (k<2048) ? bbeta[k] : bd[k-2048]; }
  else if (idx < 5632){ int k = idx-4608; bhc[k] = (k<512) ? bh0[k] : bc0[k-512]; }
}

// ---------- per-step fused attention (512 threads) ----------
__global__ __launch_bounds__(512) void attn_k(
    const u16* __restrict__ att1, const float* __restrict__ y0p,
    const float* __restrict__ wf, const float* __restrict__ bfp,
    const u16* __restrict__ enc, const int* __restrict__ declen, int t,
    u16* __restrict__ xh, float* __restrict__ alph_out)
{
  __shared__ float att2t[512], wft[512], sc[196], alps[196], red[512], awe[2][2048];
  const int b = blockIdx.x, tid = threadIdx.x;
  {
    int l = tid>>3, q = tid&7;
    float a2 = y0p[b*2560 + 2048 + tid] + y0p[64*2560 + b*2560 + 2048 + tid];
    att2t[q*64 + l] = a2;
    wft[q*64 + l] = wf[tid];
  }
  __syncthreads();
  const int w = tid>>6, lane = tid&63;
  const float bfv = bfp[0];
  for (int p = w; p < 196; p += 8) {
    s16x8 v = *(const s16x8*)(att1 + (((long)(b*196 + p))<<9) + lane*8);
    float s = 0.f;
    #pragma unroll
    for (int q=0;q<8;++q){
      float x = bf2f((u16)v[q]) + att2t[q*64 + lane];
      x = fmaxf(x, 0.f);
      s += x * wft[q*64 + lane];
    }
    #pragma unroll
    for (int off=32; off; off>>=1) s += __shfl_xor(s, off);
    if (lane==0) sc[p] = s + bfv;
  }
  __syncthreads();
  float v = (tid<196) ? sc[tid] : -3.4e38f;
  red[tid] = v; __syncthreads();
  #pragma unroll
  for (int s2=256; s2>0; s2>>=1){ if (tid<s2) red[tid] = fmaxf(red[tid], red[tid+s2]); __syncthreads(); }
  float mx = red[0];
  __syncthreads();
  float e = (tid<196) ? __expf(v - mx) : 0.f;
  red[tid] = e; __syncthreads();
  #pragma unroll
  for (int s2=256; s2>0; s2>>=1){ if (tid<s2) red[tid] += red[tid+s2]; __syncthreads(); }
  float inv = 1.f / red[0];
  if (tid < 196){
    float a = e * inv;
    alps[tid] = a;
    alph_out[((long)b*20 + t)*196 + tid] = (declen[b] > t) ? a : 0.f;
  }
  __syncthreads();
  const int half = tid>>8, tl = tid&255, d0 = tl*8;
  float acc[8] = {0,0,0,0,0,0,0,0};
  const u16* ebase = enc + (((long)b*196 + half*98)<<11) + d0;
  for (int p=0;p<98;++p){
    s16x8 ev = *(const s16x8*)(ebase + ((long)p<<11));
    float a = alps[half*98 + p];
    #pragma unroll
    for (int q=0;q<8;++q) acc[q] += a * bf2f((u16)ev[q]);
  }
  #pragma unroll
  for (int q=0;q<8;++q) awe[half][d0+q] = acc[q];
  __syncthreads();
  if (tid < 256){
    u16 o[8];
    #pragma unroll
    for (int q=0;q<8;++q){
      float vv = awe[0][d0+q] + awe[1][d0+q];
      float gate = sigm(y0p[b*2560 + d0 + q] + y0p[64*2560 + b*2560 + d0 + q]);
      o[q] = f2bf(gate * vv);
    }
    *(s16x8*)(xh + (long)b*2560 + d0) = *(s16x8*)o;
  }
}

// ---------- workspace layout (bytes) ----------
static constexpr long OFF_ENC   = 0;                 // 64*196*2048 bf16
static constexpr long OFF_ATT1  = 51380224;          // 12544*512 bf16
static constexpr long OFF_WOUTT = 64225280;          // 32000*512 bf16
static constexpr long OFF_WET   = 96993280;          // 512*2048 bf16
static constexpr long OFF_WMISC = 99090432;          // 2560*512 bf16 (Wbeta^T ; Wd^T)
static constexpr long OFF_WHC   = 101711872;         // 1024*2048 bf16 -- REUSED as PART after setup
static constexpr long OFF_WCAT2 = 105906176;         // 2048*2560 bf16 (perm [Wih_a|Whh])
static constexpr long OFF_WIHE  = 116391936;         // 2048*512 bf16 (perm Wih_e)
static constexpr long OFF_EMBB  = 118489088;         // 1280*512 bf16
static constexpr long OFF_GST   = 119799808;         // 1280*2048 f32
static constexpr long OFF_HALL  = 130285568;         // 1280*512 bf16
static constexpr long OFF_MEANB = 131596288;         // 64*2048 bf16
static constexpr long OFF_XHA   = 131858432;         // 64*2560 bf16
static constexpr long OFF_XHB   = 132186112;         // 64*2560 bf16
static constexpr long OFF_C     = 132513792;         // 64*512 f32
static constexpr long OFF_Y0P   = 132644864;         // 2*64*2560 f32
static constexpr long OFF_BSTAT = 133955584;         // 2048 f32
static constexpr long OFF_BMISC = 133963776;         // 2560 f32
static constexpr long OFF_BHC   = 133974016;         // 1024 f32
static constexpr long OFF_SIDX  = 133978112;         // 64 int
static constexpr long OFF_DECL  = 133978368;         // 64 int
static constexpr long OFF_CNT   = 133978624;         // 20*64 int
static constexpr long OFF_PART  = OFF_WHC;           // 8*64*2048 f32 (4 MB, after setup)

extern "C" void kernel_launch(void* const* d_in, const int* in_sizes, int n_in,
                              void* d_out, int out_size, void* d_ws, size_t ws_size,
                              hipStream_t stream)
{
  (void)in_sizes; (void)n_in; (void)out_size; (void)ws_size;
  const float* features = (const float*)d_in[0];
  const int*   captions = (const int*)d_in[1];
  const int*   caplen   = (const int*)d_in[2];
  const float* embW     = (const float*)d_in[3];
  const float* We       = (const float*)d_in[4];
  const float* be       = (const float*)d_in[5];
  const float* Wd       = (const float*)d_in[6];
  const float* bd       = (const float*)d_in[7];
  const float* wf       = (const float*)d_in[8];
  const float* bfp      = (const float*)d_in[9];
  const float* Wih      = (const float*)d_in[10];
  const float* Whh      = (const float*)d_in[11];
  const float* bih      = (const float*)d_in[12];
  const float* bhh      = (const float*)d_in[13];
  const float* Wh0      = (const float*)d_in[14];
  const float* bh0      = (const float*)d_in[15];
  const float* Wc0      = (const float*)d_in[16];
  const float* bc0      = (const float*)d_in[17];
  const float* Wbeta    = (const float*)d_in[18];
  const float* bbeta    = (const float*)d_in[19];
  const float* Wout     = (const float*)d_in[20];
  const float* bout     = (const float*)d_in[21];

  char* ws = (char*)d_ws;
  u16*   enc   = (u16*)(ws + OFF_ENC);
  u16*   att1  = (u16*)(ws + OFF_ATT1);
  u16*   woutt = (u16*)(ws + OFF_WOUTT);
  u16*   wet   = (u16*)(ws + OFF_WET);
  u16*   wmisc = (u16*)(ws + OFF_WMISC);
  u16*   whc   = (u16*)(ws + OFF_WHC);
  u16*   wcat2 = (u16*)(ws + OFF_WCAT2);
  u16*   wihe  = (u16*)(ws + OFF_WIHE);
  u16*   embb  = (u16*)(ws + OFF_EMBB);
  float* gst   = (float*)(ws + OFF_GST);
  u16*   hall  = (u16*)(ws + OFF_HALL);
  u16*   meanb = (u16*)(ws + OFF_MEANB);
  u16*   xhA   = (u16*)(ws + OFF_XHA);
  u16*   xhB   = (u16*)(ws + OFF_XHB);
  float* cbuf  = (float*)(ws + OFF_C);
  float* y0p   = (float*)(ws + OFF_Y0P);
  float* bstat = (float*)(ws + OFF_BSTAT);
  float* bmisc = (float*)(ws + OFF_BMISC);
  float* bhc   = (float*)(ws + OFF_BHC);
  int*   sidx  = (int*)(ws + OFF_SIDX);
  int*   declen= (int*)(ws + OFF_DECL);
  int*   cnt   = (int*)(ws + OFF_CNT);
  float* part  = (float*)(ws + OFF_PART);

  float* outP    = (float*)d_out;            // [64][20][32000]
  float* outCaps = outP + 40960000;          // [64][22]
  float* outLens = outCaps + 1408;           // [64]
  float* outAlph = outLens + 64;             // [64][20][196]
  float* outSidx = outAlph + 250880;         // [64]

  // ---- setup ----
  sort_k<<<1,64,0,stream>>>(caplen, captions, sidx, declen, outCaps, outLens, outSidx, cnt);
  prep_enc<<<128,256,0,stream>>>(features, sidx, enc, meanb);
  emb_gather<<<320,256,0,stream>>>(captions, sidx, embW, embb);
  transpose_bf16<<<dim3(8,32),256,0,stream>>>(We,    wet,              2048, 512);
  transpose_bf16<<<dim3(32,8),256,0,stream>>>(Wbeta, wmisc,            512, 2048);
  transpose_bf16<<<dim3(8,8), 256,0,stream>>>(Wd,    wmisc + 2048*512, 512, 512);
  transpose_bf16<<<dim3(8,32),256,0,stream>>>(Wh0,   whc,              2048, 512);
  transpose_bf16<<<dim3(8,32),256,0,stream>>>(Wc0,   whc + 512*2048,   2048, 512);
  transpose_bf16<<<dim3(500,8),256,0,stream>>>(Wout, woutt,            512, 32000);
  build_wcat2<<<2560,256,0,stream>>>(Wih, Whh, wcat2);
  build_wihe<<<512,256,0,stream>>>(Wih, wihe);
  build_bias<<<22,256,0,stream>>>(bih,bhh,bbeta,bd,bh0,bc0,bstat,bmisc,bhc);

  // h0/c0 : mean @ [Wh0|Wc0]   (must precede any PART use: whc region reused)
  { EpiParams ep{}; ep.bias0 = bhc; ep.xh = xhA; ep.c = cbuf;
    gemm_bt<64,64,EPI_H0C0,1,false><<<dim3(16,1),256,0,stream>>>(meanb, 2048, whc, 2048, 2048, ep); }
  // att1 = enc @ We + be  (bf16 out); SWAPXY: x = m-tiles
  { EpiParams ep{}; ep.outb = att1; ep.ldo = 512; ep.bias0 = be;
    gemm_bt<128,128,EPI_BF16,1,true><<<dim3(98,4),256,0,stream>>>(enc, 2048, wet, 2048, 2048, ep); }
  // g_static[t,b,:] = e_t @ Wih_e^T + bih + bhh (permuted cols)
  { EpiParams ep{}; ep.out0 = gst; ep.ldo = 2048; ep.bias0 = bstat;
    gemm_bt<128,64,EPI_F32,1,false><<<dim3(32,10),256,0,stream>>>(embb, 512, wihe, 512, 512, ep); }

  // ---- 20 sequential steps ----
  for (int t=0; t<20; ++t){
    u16* cur = (t&1) ? xhB : xhA;
    u16* nxt = (t&1) ? xhA : xhB;
    { EpiParams ep{}; ep.out0 = y0p; ep.ldo = 2560; ep.pstride = 64*2560; ep.bias0 = bmisc;
      gemm_bt<64,64,EPI_F32,2,false><<<dim3(40,2),256,0,stream>>>(cur + 2048, 2560, wmisc, 512, 512, ep); }
    attn_k<<<64,512,0,stream>>>(att1, y0p, wf, bfp, enc, declen, t, cur, outAlph);
    { EpiParams ep{}; ep.gst = gst; ep.t = t; ep.c = cbuf; ep.xh = nxt; ep.hall = hall;
      ep.part = part; ep.cnt = cnt;
      gemm_bt<64,32,EPI_LSTM,8,false><<<dim3(64,8),256,0,stream>>>(cur, 2560, wcat2, 2560, 2560, ep); }
  }

  // ---- batched predictions: h_all @ Wout + bout, masked; SWAPXY for B-panel reuse ----
  { EpiParams ep{}; ep.out0 = outP; ep.bias0 = bout; ep.declen = declen;
    gemm_bt<128,128,EPI_PREDS,1,true><<<dim3(10,250),256,0,stream>>>(hall, 512, woutt, 512, 512, ep); }
}

// Round 3
// 1992.008 us; speedup vs baseline: 1.2954x; 1.0745x over previous
//
#include <hip/hip_runtime.h>
#include <stdint.h>

// ---------- types / helpers ----------
typedef short s16x8 __attribute__((ext_vector_type(8)));
typedef short s16x4 __attribute__((ext_vector_type(4)));
typedef float f32x4 __attribute__((ext_vector_type(4)));
typedef unsigned short u16;

#define DEV __device__ __forceinline__

DEV float bf2f(u16 v){ union{float f; unsigned u;} x; x.u = ((unsigned)v)<<16; return x.f; }
DEV u16 f2bf(float f){ union{float f; unsigned u;} x; x.f = f; unsigned r = x.u + 0x7fffu + ((x.u>>16)&1u); return (u16)(r>>16); }
DEV float sigm(float x){ return 1.f/(1.f + __expf(-x)); }

// B=64, P=196, D=2048, E=512, H=512, A=512, V=32000, S=22, T=20

enum { EPI_F32=0, EPI_BF16=1, EPI_H0C0=2, EPI_PREDS=3, EPI_LSTM=4 };

struct EpiParams {
  float* out0; long ldo; long pstride;
  u16* outb;
  const float* bias0;
  const int* declen;
  float* c; u16* xh; u16* hall;
  const float* gst; int t;
  float* part; int* cnt;
};

// ---------- generic MFMA GEMM: C[M][N] = A[M][K](bf16) * B[N][K](bf16)^T ----------
// 2-phase reg-staged prefetch; optional split-K (BM must be 64, blockIdx.y = split);
// optional SWAPXY; optional SWZM>0: 1D grid, bijective XCD-chunked swizzle with
// SWZM m-tiles iterating fastest inside each XCD chunk (B-panel L2 locality).
template<int BM, int BN, int EPI, int KSPLIT, bool SWAPXY, int SWZM>
__global__ __launch_bounds__(256) void gemm_bt(
    const u16* __restrict__ A, long lda,
    const u16* __restrict__ B, long ldb,
    int K, EpiParams ep)
{
  constexpr int MF = BM/64;          // m-fragments per wave
  constexpr int NF = BN/16;          // n-fragments per wave
  constexpr int CHA = BM*8, CH = CHA + BN*8;   // 16B chunks per K-tile
  constexpr int NST = CH/256;        // staging chunks per thread
  __shared__ char smem[(BM+BN)*128];
  const int tid = threadIdx.x;
  const int w = tid>>6, lane = tid&63;

  int split = 0;
  long arow0, brow0;
  if constexpr (SWZM > 0) {
    int id = blockIdx.x, tot = gridDim.x;
    int q = tot>>3, r = tot&7, xcd = id&7, idx = id>>3;
    int cid = (xcd<r) ? xcd*(q+1)+idx : r*(q+1)+(xcd-r)*q+idx;
    arow0 = (long)(cid % SWZM)*BM; brow0 = (long)(cid / SWZM)*BN;
  } else if constexpr (KSPLIT > 1) { split = blockIdx.y; arow0 = 0; brow0 = (long)blockIdx.x*BN; }
  else if constexpr (SWAPXY) { arow0 = (long)blockIdx.x*BM; brow0 = (long)blockIdx.y*BN; }
  else { arow0 = (long)blockIdx.y*BM; brow0 = (long)blockIdx.x*BN; }

  // precompute per-chunk source pointers and swizzled LDS offsets
  const u16* gsrc[NST]; int ldst[NST];
  #pragma unroll
  for (int i=0;i<NST;++i){
    int c = i*256 + tid;
    if (i*256 < CHA){
      int row = c>>3, k16 = c&7;
      gsrc[i] = A + (arow0+row)*lda + k16*8;
      ldst[i] = row*128 + ((k16*16) ^ ((row&7)<<4));
    } else {
      int cb = c - CHA; int row = cb>>3, k16 = cb&7;
      gsrc[i] = B + (brow0+row)*ldb + k16*8;
      ldst[i] = BM*128 + row*128 + ((k16*16) ^ ((row&7)<<4));
    }
  }

  f32x4 acc[MF][NF];
  #pragma unroll
  for (int i=0;i<MF;++i)
    #pragma unroll
    for (int j=0;j<NF;++j) acc[i][j] = (f32x4){0.f,0.f,0.f,0.f};

  const int KT = K >> 6;
  const int nkt = (KSPLIT>1) ? (KT/KSPLIT) : KT;
  const int kt0 = (KSPLIT>1) ? split*nkt : 0;

  s16x8 st[NST];
  #pragma unroll
  for (int i=0;i<NST;++i) st[i] = *(const s16x8*)(gsrc[i] + (long)kt0*64);

  char* Al = smem;
  for (int kk=0; kk<nkt; ++kk){
    #pragma unroll
    for (int i=0;i<NST;++i) *(s16x8*)(smem + ldst[i]) = st[i];
    __syncthreads();
    if (kk+1 < nkt){
      long kb = (long)(kt0+kk+1)*64;
      #pragma unroll
      for (int i=0;i<NST;++i) st[i] = *(const s16x8*)(gsrc[i] + kb);
    }
    #pragma unroll
    for (int ks = 0; ks < 2; ++ks) {
      s16x8 af[MF], bfr[NF];
      const int kboff = ks*64 + ((lane>>4)<<4);
      #pragma unroll
      for (int mf=0; mf<MF; ++mf) {
        int r = w*(16*MF) + mf*16 + (lane&15);
        af[mf] = *(const s16x8*)(Al + r*128 + (kboff ^ ((r&7)<<4)));
      }
      #pragma unroll
      for (int nf=0; nf<NF; ++nf) {
        int r = nf*16 + (lane&15);
        bfr[nf] = *(const s16x8*)(Al + BM*128 + r*128 + (kboff ^ ((r&7)<<4)));
      }
      #pragma unroll
      for (int mf=0; mf<MF; ++mf)
        #pragma unroll
        for (int nf=0; nf<NF; ++nf)
          acc[mf][nf] = __builtin_amdgcn_mfma_f32_16x16x32_bf16(af[mf], bfr[nf], acc[mf][nf], 0,0,0);
    }
    __syncthreads();
  }

  if constexpr (EPI == EPI_LSTM) {
    // split-K partial write (BM=64, NF=2)
    float* PS = ep.part + (long)split*(64*2048);
    #pragma unroll
    for (int nf=0; nf<NF; ++nf)
      #pragma unroll
      for (int r=0; r<4; ++r) {
        int ml = w*16 + ((lane>>4)<<2) + r;
        int nl = nf*16 + (lane&15);
        PS[ml*2048 + brow0 + nl] = acc[0][nf][r];
      }
    __threadfence();
    __shared__ int lastf;
    if (tid==0){ int v = atomicAdd(ep.cnt + ep.t*64 + blockIdx.x, 1); lastf = (v == KSPLIT-1); }
    __syncthreads();
    if (!lastf) return;
    __threadfence();
    const int j0 = (int)(brow0 >> 2);
    for (int it = tid; it < 512; it += 256){
      int b = it>>3, jl = it&7, j = j0 + jl;
      float g4[4];
      #pragma unroll
      for (int gi=0; gi<4; ++gi){
        long n = brow0 + jl*4 + gi;
        float s = ep.gst[((long)ep.t*64 + b)*2048 + n];
        #pragma unroll
        for (int sp=0; sp<KSPLIT; ++sp)
          s += __hip_atomic_load(ep.part + (long)sp*(64*2048) + (long)b*2048 + n,
                                 __ATOMIC_RELAXED, __HIP_MEMORY_SCOPE_AGENT);
        g4[gi] = s;
      }
      float cc = ep.c[b*512 + j];
      float cn = sigm(g4[1])*cc + sigm(g4[0])*tanhf(g4[2]);
      float hn = sigm(g4[3])*tanhf(cn);
      ep.c[b*512 + j] = cn;
      u16 hb = f2bf(hn);
      ep.xh[b*2560 + 2048 + j] = hb;                 // NEXT step's xh buffer
      ep.hall[((long)ep.t*64 + b)*512 + j] = hb;
    }
  } else {
    #pragma unroll
    for (int mf=0; mf<MF; ++mf)
      #pragma unroll
      for (int nf=0; nf<NF; ++nf)
        #pragma unroll
        for (int r=0; r<4; ++r) {
          long m = arow0 + w*(16*MF) + mf*16 + ((lane>>4)<<2) + r;
          long n = brow0 + nf*16 + (lane&15);
          float bv = ep.bias0[n];
          if constexpr (EPI == EPI_F32) { if (split != 0) bv = 0.f; }
          float v = acc[mf][nf][r] + bv;
          if constexpr (EPI == EPI_F32) {
            ep.out0[(long)split*ep.pstride + m*ep.ldo + n] = v;
          } else if constexpr (EPI == EPI_BF16) {
            ep.outb[m*ep.ldo + n] = f2bf(v);
          } else if constexpr (EPI == EPI_H0C0) {
            if (n < 512) ep.xh[m*2560 + 2048 + n] = f2bf(v);   // h0
            else         ep.c[m*512 + (n-512)] = v;            // c0
          } else { // EPI_PREDS : m = t*64+b -> out[b][t][n], masked, nontemporal
            int t = (int)(m>>6), b = (int)(m&63);
            float ov = (ep.declen[b] > t) ? v : 0.f;
            __builtin_nontemporal_store(ov, &ep.out0[(long)b*640000 + (long)t*32000 + n]);
          }
        }
  }
}

// ---------- transpose f32[R][C] -> bf16[C][R] ----------
__global__ __launch_bounds__(256) void transpose_bf16(
    const float* __restrict__ in, u16* __restrict__ out, int R, int C)
{
  __shared__ float t[64][65];
  const int bx = blockIdx.x*64, by = blockIdx.y*64;
  const int tx = threadIdx.x & 63, ty = threadIdx.x >> 6;
  #pragma unroll
  for (int i=0;i<16;++i){ int r = i*4+ty; t[r][tx] = in[(long)(by+r)*C + bx+tx]; }
  __syncthreads();
  #pragma unroll
  for (int i=0;i<16;++i){ int cc = i*4+ty; out[(long)(bx+cc)*R + by+tx] = f2bf(t[tx][cc]); }
}

// ---------- stable descending argsort of 64 lengths + small outputs + cnt zero ----------
__global__ void sort_k(const int* __restrict__ cl, const int* __restrict__ captions,
                       int* __restrict__ sidx, int* __restrict__ declen,
                       float* __restrict__ outCaps, float* __restrict__ outLens,
                       float* __restrict__ outSidx, int* __restrict__ cnt)
{
  __shared__ int s_idx[64];
  int i = threadIdx.x;
  int li = cl[i];
  int rank = 0;
  for (int j=0;j<64;++j){ int lj = cl[j]; rank += (lj>li) || (lj==li && j<i); }
  s_idx[rank] = i;
  __syncthreads();
  int src = s_idx[i];
  sidx[i] = src;
  int L = cl[src];
  declen[i] = L - 1;
  outLens[i] = (float)L;
  outSidx[i] = (float)src;
  for (int s=0;s<22;++s) outCaps[i*22+s] = (float)captions[s*64 + src];
  for (int s=0;s<20;++s) cnt[s*64 + i] = 0;
}

// ---------- gather sorted enc -> bf16 + per-(b,d) mean (512 blocks) ----------
__global__ __launch_bounds__(256) void prep_enc(
    const float* __restrict__ features, const int* __restrict__ sidx,
    u16* __restrict__ enc, u16* __restrict__ meanb)
{
  __shared__ float red[4][256];
  int b = blockIdx.x >> 3, oct = blockIdx.x & 7;
  int lv = threadIdx.x & 63, g = threadIdx.x >> 6;
  int d0 = oct*256 + lv*4;
  const float* src = features + (long)sidx[b]*(196*2048) + d0;
  float acc[4] = {0.f,0.f,0.f,0.f};
  for (int p=g; p<196; p+=4){
    f32x4 v = *(const f32x4*)(src + (long)p*2048);
    u16 o[4];
    #pragma unroll
    for (int q=0;q<4;++q){ acc[q] += v[q]; o[q] = f2bf(v[q]); }
    *(s16x4*)(enc + ((long)b*196 + p)*2048 + d0) = *(s16x4*)o;
  }
  #pragma unroll
  for (int q=0;q<4;++q) red[g][lv*4+q] = acc[q];
  __syncthreads();
  if (threadIdx.x < 64){
    u16 mo[4];
    #pragma unroll
    for (int q=0;q<4;++q){
      float s = red[0][threadIdx.x*4+q] + red[1][threadIdx.x*4+q]
              + red[2][threadIdx.x*4+q] + red[3][threadIdx.x*4+q];
      mo[q] = f2bf(s*(1.f/196.f));
    }
    *(s16x4*)(meanb + b*2048 + oct*256 + threadIdx.x*4) = *(s16x4*)mo;
  }
}

// ---------- gather embeddings for t<20 -> bf16 [t*64+b][512] ----------
__global__ void emb_gather(const int* __restrict__ captions, const int* __restrict__ sidx,
                           const float* __restrict__ embW, u16* __restrict__ out)
{
  int idx = blockIdx.x*256 + threadIdx.x;      // 1280*64
  int row = idx >> 6; int e0 = (idx & 63)*8;
  int t = row >> 6, b = row & 63;
  int tok = captions[t*64 + sidx[b]];
  const float* s = embW + (long)tok*512 + e0;
  f32x4 v0 = *(const f32x4*)s, v1 = *(const f32x4*)(s+4);
  u16 o[8];
  #pragma unroll
  for (int q=0;q<4;++q){ o[q] = f2bf(v0[q]); o[4+q] = f2bf(v1[q]); }
  *(s16x8*)(out + (long)row*512 + e0) = *(s16x8*)o;
}

// ---------- weight packers ----------
__global__ void build_wcat2(const float* __restrict__ Wih, const float* __restrict__ Whh,
                            u16* __restrict__ out)
{
  long idx = (long)blockIdx.x*256 + threadIdx.x;   // 2048*320
  int r = (int)(idx / 320);
  int kc = (int)(idx % 320) * 8;
  int j = r>>2, g = r&3;
  int orow = g*512 + j;
  const float* s = (kc < 2048) ? (Wih + (long)orow*2560 + 512 + kc)
                               : (Whh + (long)orow*512 + (kc - 2048));
  f32x4 v0 = *(const f32x4*)s, v1 = *(const f32x4*)(s+4);
  u16 o[8];
  #pragma unroll
  for (int q=0;q<4;++q){ o[q] = f2bf(v0[q]); o[4+q] = f2bf(v1[q]); }
  *(s16x8*)(out + (long)r*2560 + kc) = *(s16x8*)o;
}

__global__ void build_wihe(const float* __restrict__ Wih, u16* __restrict__ out)
{
  int idx = blockIdx.x*256 + threadIdx.x;          // 2048*64
  int r = idx >> 6; int kc = (idx & 63)*8;
  int j = r>>2, g = r&3;
  const float* s = Wih + (long)(g*512+j)*2560 + kc;
  f32x4 v0 = *(const f32x4*)s, v1 = *(const f32x4*)(s+4);
  u16 o[8];
  #pragma unroll
  for (int q=0;q<4;++q){ o[q] = f2bf(v0[q]); o[4+q] = f2bf(v1[q]); }
  *(s16x8*)(out + (long)r*512 + kc) = *(s16x8*)o;
}

__global__ void build_bias(const float* bih, const float* bhh, const float* bbeta,
                           const float* bd, const float* bh0, const float* bc0,
                           float* bstat, float* bmisc, float* bhc)
{
  int idx = blockIdx.x*256 + threadIdx.x;
  if (idx < 2048){ int j = idx>>2, g = idx&3; bstat[idx] = bih[g*512+j] + bhh[g*512+j]; }
  else if (idx < 4608){ int k = idx-2048; bmisc[k] = (k<2048) ? bbeta[k] : bd[k-2048]; }
  else if (idx < 5632){ int k = idx-4608; bhc[k] = (k<512) ? bh0[k] : bc0[k-512]; }
}

// ---------- step kernel 1: scores (256 blocks = 64 b x 4 p-slices) ----------
__global__ __launch_bounds__(256) void attn_scores(
    const u16* __restrict__ att1, const float* __restrict__ y0p,
    const float* __restrict__ wf, const float* __restrict__ bfp,
    float* __restrict__ sc_g)
{
  __shared__ float att2t[512], wft[512];
  const int b = blockIdx.x >> 2, s = blockIdx.x & 3;
  const int tid = threadIdx.x;
  for (int idx = tid; idx < 512; idx += 256){
    int l = idx>>3, q = idx&7;
    att2t[q*64 + l] = y0p[b*2560 + 2048 + idx] + y0p[64*2560 + b*2560 + 2048 + idx];
    wft[q*64 + l] = wf[idx];
  }
  __syncthreads();
  const int w = tid>>6, lane = tid&63;
  const float bfv = bfp[0];
  const int p0 = s*49;
  for (int p = p0 + w; p < p0 + 49; p += 4) {
    s16x8 v = *(const s16x8*)(att1 + (((long)(b*196 + p))<<9) + lane*8);
    float sa = 0.f;
    #pragma unroll
    for (int q=0;q<8;++q){
      float x = bf2f((u16)v[q]) + att2t[q*64 + lane];
      x = fmaxf(x, 0.f);
      sa += x * wft[q*64 + lane];
    }
    #pragma unroll
    for (int off=32; off; off>>=1) sa += __shfl_xor(sa, off);
    if (lane==0) sc_g[b*196 + p] = sa + bfv;
  }
}

// ---------- step kernel 2: softmax + awe + gate (256 blocks = 64 b x 4 d-slices) ----------
__global__ __launch_bounds__(512) void attn_awe(
    const float* __restrict__ sc_g, const float* __restrict__ y0p,
    const u16* __restrict__ enc, const int* __restrict__ declen, int t,
    u16* __restrict__ xh, float* __restrict__ alph_out)
{
  __shared__ float alps[196], red[512], awe_p[8][512];
  const int b = blockIdx.x >> 2, s = blockIdx.x & 3;
  const int tid = threadIdx.x;
  float v = (tid<196) ? sc_g[b*196 + tid] : -3.4e38f;
  red[tid] = v; __syncthreads();
  #pragma unroll
  for (int s2=256; s2>0; s2>>=1){ if (tid<s2) red[tid] = fmaxf(red[tid], red[tid+s2]); __syncthreads(); }
  float mx = red[0];
  __syncthreads();
  float e = (tid<196) ? __expf(v - mx) : 0.f;
  red[tid] = e; __syncthreads();
  #pragma unroll
  for (int s2=256; s2>0; s2>>=1){ if (tid<s2) red[tid] += red[tid+s2]; __syncthreads(); }
  float inv = 1.f / red[0];
  if (tid < 196){
    float a = e * inv;
    alps[tid] = a;
    if (s == 0) alph_out[((long)b*20 + t)*196 + tid] = (declen[b] > t) ? a : 0.f;
  }
  __syncthreads();
  const int lv = tid & 63, g = tid >> 6;
  const int d0 = s*512 + lv*8;
  const u16* ebase = enc + (((long)b*196)<<11) + d0;
  float acc[8] = {0,0,0,0,0,0,0,0};
  #pragma unroll 4
  for (int p=g; p<196; p+=8){
    s16x8 ev = *(const s16x8*)(ebase + ((long)p<<11));
    float a = alps[p];
    #pragma unroll
    for (int q=0;q<8;++q) acc[q] += a * bf2f((u16)ev[q]);
  }
  f32x4 lo = {acc[0],acc[1],acc[2],acc[3]}, hi = {acc[4],acc[5],acc[6],acc[7]};
  *(f32x4*)&awe_p[g][lv*8]   = lo;
  *(f32x4*)&awe_p[g][lv*8+4] = hi;
  __syncthreads();
  {
    int c = tid;                       // 0..511
    float sum = 0.f;
    #pragma unroll
    for (int gg=0; gg<8; ++gg) sum += awe_p[gg][c];
    int dcol = s*512 + c;
    float gate = sigm(y0p[b*2560 + dcol] + y0p[64*2560 + b*2560 + dcol]);
    xh[(long)b*2560 + dcol] = f2bf(gate * sum);
  }
}

// ---------- workspace layout (bytes) ----------
static constexpr long OFF_ENC   = 0;                 // 64*196*2048 bf16
static constexpr long OFF_ATT1  = 51380224;          // 12544*512 bf16
static constexpr long OFF_WOUTT = 64225280;          // 32000*512 bf16
static constexpr long OFF_WET   = 96993280;          // 512*2048 bf16
static constexpr long OFF_WMISC = 99090432;          // 2560*512 bf16 (Wbeta^T ; Wd^T)
static constexpr long OFF_WHC   = 101711872;         // 1024*2048 bf16 -- REUSED as PART after setup
static constexpr long OFF_WCAT2 = 105906176;         // 2048*2560 bf16 (perm [Wih_a|Whh])
static constexpr long OFF_WIHE  = 116391936;         // 2048*512 bf16 (perm Wih_e)
static constexpr long OFF_EMBB  = 118489088;         // 1280*512 bf16
static constexpr long OFF_GST   = 119799808;         // 1280*2048 f32
static constexpr long OFF_HALL  = 130285568;         // 1280*512 bf16
static constexpr long OFF_MEANB = 131596288;         // 64*2048 bf16
static constexpr long OFF_XHA   = 131858432;         // 64*2560 bf16
static constexpr long OFF_XHB   = 132186112;         // 64*2560 bf16
static constexpr long OFF_C     = 132513792;         // 64*512 f32
static constexpr long OFF_Y0P   = 132644864;         // 2*64*2560 f32
static constexpr long OFF_BSTAT = 133955584;         // 2048 f32
static constexpr long OFF_BMISC = 133963776;         // 2560 f32
static constexpr long OFF_BHC   = 133974016;         // 1024 f32
static constexpr long OFF_SIDX  = 133978112;         // 64 int
static constexpr long OFF_DECL  = 133978368;         // 64 int
static constexpr long OFF_CNT   = 133978624;         // 20*64 int
static constexpr long OFF_SCG   = 133983744;         // 64*196 f32
static constexpr long OFF_PART  = OFF_WHC;           // 8*64*2048 f32 (4 MB, after setup)

extern "C" void kernel_launch(void* const* d_in, const int* in_sizes, int n_in,
                              void* d_out, int out_size, void* d_ws, size_t ws_size,
                              hipStream_t stream)
{
  (void)in_sizes; (void)n_in; (void)out_size; (void)ws_size;
  const float* features = (const float*)d_in[0];
  const int*   captions = (const int*)d_in[1];
  const int*   caplen   = (const int*)d_in[2];
  const float* embW     = (const float*)d_in[3];
  const float* We       = (const float*)d_in[4];
  const float* be       = (const float*)d_in[5];
  const float* Wd       = (const float*)d_in[6];
  const float* bd       = (const float*)d_in[7];
  const float* wf       = (const float*)d_in[8];
  const float* bfp      = (const float*)d_in[9];
  const float* Wih      = (const float*)d_in[10];
  const float* Whh      = (const float*)d_in[11];
  const float* bih      = (const float*)d_in[12];
  const float* bhh      = (const float*)d_in[13];
  const float* Wh0      = (const float*)d_in[14];
  const float* bh0      = (const float*)d_in[15];
  const float* Wc0      = (const float*)d_in[16];
  const float* bc0      = (const float*)d_in[17];
  const float* Wbeta    = (const float*)d_in[18];
  const float* bbeta    = (const float*)d_in[19];
  const float* Wout     = (const float*)d_in[20];
  const float* bout     = (const float*)d_in[21];

  char* ws = (char*)d_ws;
  u16*   enc   = (u16*)(ws + OFF_ENC);
  u16*   att1  = (u16*)(ws + OFF_ATT1);
  u16*   woutt = (u16*)(ws + OFF_WOUTT);
  u16*   wet   = (u16*)(ws + OFF_WET);
  u16*   wmisc = (u16*)(ws + OFF_WMISC);
  u16*   whc   = (u16*)(ws + OFF_WHC);
  u16*   wcat2 = (u16*)(ws + OFF_WCAT2);
  u16*   wihe  = (u16*)(ws + OFF_WIHE);
  u16*   embb  = (u16*)(ws + OFF_EMBB);
  float* gst   = (float*)(ws + OFF_GST);
  u16*   hall  = (u16*)(ws + OFF_HALL);
  u16*   meanb = (u16*)(ws + OFF_MEANB);
  u16*   xhA   = (u16*)(ws + OFF_XHA);
  u16*   xhB   = (u16*)(ws + OFF_XHB);
  float* cbuf  = (float*)(ws + OFF_C);
  float* y0p   = (float*)(ws + OFF_Y0P);
  float* bstat = (float*)(ws + OFF_BSTAT);
  float* bmisc = (float*)(ws + OFF_BMISC);
  float* bhc   = (float*)(ws + OFF_BHC);
  int*   sidx  = (int*)(ws + OFF_SIDX);
  int*   declen= (int*)(ws + OFF_DECL);
  int*   cnt   = (int*)(ws + OFF_CNT);
  float* scg   = (float*)(ws + OFF_SCG);
  float* part  = (float*)(ws + OFF_PART);

  float* outP    = (float*)d_out;            // [64][20][32000]
  float* outCaps = outP + 40960000;          // [64][22]
  float* outLens = outCaps + 1408;           // [64]
  float* outAlph = outLens + 64;             // [64][20][196]
  float* outSidx = outAlph + 250880;         // [64]

  // ---- setup ----
  sort_k<<<1,64,0,stream>>>(caplen, captions, sidx, declen, outCaps, outLens, outSidx, cnt);
  prep_enc<<<512,256,0,stream>>>(features, sidx, enc, meanb);
  emb_gather<<<320,256,0,stream>>>(captions, sidx, embW, embb);
  transpose_bf16<<<dim3(8,32),256,0,stream>>>(We,    wet,              2048, 512);
  transpose_bf16<<<dim3(32,8),256,0,stream>>>(Wbeta, wmisc,            512, 2048);
  transpose_bf16<<<dim3(8,8), 256,0,stream>>>(Wd,    wmisc + 2048*512, 512, 512);
  transpose_bf16<<<dim3(8,32),256,0,stream>>>(Wh0,   whc,              2048, 512);
  transpose_bf16<<<dim3(8,32),256,0,stream>>>(Wc0,   whc + 512*2048,   2048, 512);
  transpose_bf16<<<dim3(500,8),256,0,stream>>>(Wout, woutt,            512, 32000);
  build_wcat2<<<2560,256,0,stream>>>(Wih, Whh, wcat2);
  build_wihe<<<512,256,0,stream>>>(Wih, wihe);
  build_bias<<<22,256,0,stream>>>(bih,bhh,bbeta,bd,bh0,bc0,bstat,bmisc,bhc);

  // h0/c0 : mean @ [Wh0|Wc0]   (must precede any PART use: whc region reused)
  { EpiParams ep{}; ep.bias0 = bhc; ep.xh = xhA; ep.c = cbuf;
    gemm_bt<64,64,EPI_H0C0,1,false,0><<<dim3(16,1),256,0,stream>>>(meanb, 2048, whc, 2048, 2048, ep); }
  // att1 = enc @ We + be  (bf16 out); SWAPXY: x = m-tiles
  { EpiParams ep{}; ep.outb = att1; ep.ldo = 512; ep.bias0 = be;
    gemm_bt<128,128,EPI_BF16,1,true,0><<<dim3(98,4),256,0,stream>>>(enc, 2048, wet, 2048, 2048, ep); }
  // g_static[t,b,:] = e_t @ Wih_e^T + bih + bhh (permuted cols)
  { EpiParams ep{}; ep.out0 = gst; ep.ldo = 2048; ep.bias0 = bstat;
    gemm_bt<128,64,EPI_F32,1,false,0><<<dim3(32,10),256,0,stream>>>(embb, 512, wihe, 512, 512, ep); }

  // ---- 20 sequential steps ----
  for (int t=0; t<20; ++t){
    u16* cur = (t&1) ? xhB : xhA;
    u16* nxt = (t&1) ? xhA : xhB;
    { EpiParams ep{}; ep.out0 = y0p; ep.ldo = 2560; ep.pstride = 64*2560; ep.bias0 = bmisc;
      gemm_bt<64,64,EPI_F32,2,false,0><<<dim3(40,2),256,0,stream>>>(cur + 2048, 2560, wmisc, 512, 512, ep); }
    attn_scores<<<256,256,0,stream>>>(att1, y0p, wf, bfp, scg);
    attn_awe<<<256,512,0,stream>>>(scg, y0p, enc, declen, t, cur, outAlph);
    { EpiParams ep{}; ep.gst = gst; ep.t = t; ep.c = cbuf; ep.xh = nxt; ep.hall = hall;
      ep.part = part; ep.cnt = cnt;
      gemm_bt<64,32,EPI_LSTM,8,false,0><<<dim3(64,8),256,0,stream>>>(cur, 2560, wcat2, 2560, 2560, ep); }
  }

  // ---- batched predictions: h_all @ Wout + bout, masked; XCD-chunked swizzle + NT stores ----
  { EpiParams ep{}; ep.out0 = outP; ep.bias0 = bout; ep.declen = declen;
    gemm_bt<128,128,EPI_PREDS,1,false,10><<<2500,256,0,stream>>>(hall, 512, woutt, 512, 512, ep); }
}